// Round 8
// baseline (1015.172 us; speedup 1.0000x reference)
//
#include <hip/hip_runtime.h>
#include <hip/hip_fp16.h>

typedef _Float16 f16;
typedef _Float16 f16x8 __attribute__((ext_vector_type(8)));
typedef float f32x4 __attribute__((ext_vector_type(4)));

#define B_SZ   4096
#define T_SZ   32
#define VOCAB  10000
#define E_SZ   300
#define H_SZ   300
#define KP     320          // embT row width (10x32)
#define GP     304          // per-gate padded N (19x16)
#define G4     1216         // 4*GP
#define LDA    328          // hbuf/xbuf row stride f16 (16B-aligned rows)
#define LDG    1224         // gates row stride f16
#define ROWS   16           // batch rows per block
#define NBLK   (B_SZ/ROWS)  // 256 blocks -> 1 per CU

__device__ __forceinline__ float sigmoid_f(float x) {
    return 1.f / (1.f + __expf(-x));
}
__device__ __forceinline__ float tanh_f(float x) {
    x = fminf(fmaxf(x, -15.f), 15.f);
    float e = __expf(2.f * x);
    return (e - 1.f) / (e + 1.f);
}

// P0: embed_w f32 [V][300] -> embT f16 [V][320] zero-padded
__global__ void kP0(const float* __restrict__ ew, f16* __restrict__ embT) {
    int v = blockIdx.x, k = threadIdx.x;           // 320 threads
    embT[(size_t)v * KP + k] = (k < E_SZ) ? (f16)ew[(size_t)v * E_SZ + k] : (f16)0.f;
}

// kPW2: pack weights into MFMA-B-fragment order, coalesced.
// Wpk block (gate,nt,k) = 1024 B; lane (c,q) holds W[n=gate*300+nt*16+c][kk=k*32+q*8..+7]
// kk<320 -> W_hh col kk, kk>=320 -> W_ih col kk-320 (zero-padded).
__global__ void kPW2(const float* __restrict__ wih, const float* __restrict__ whh,
                     const float* __restrict__ bih, const float* __restrict__ bhh,
                     f16* __restrict__ Wpk, float* __restrict__ biasp) {
    int bid = blockIdx.x;                          // 0..1519 = (gate*19+nt)*20+k
    int lane = threadIdx.x;                        // 64
    int k = bid % 20, ntg = bid / 20;
    int nt = ntg % 19, gate = ntg / 19;
    int c = lane & 15, q = lane >> 4;
    int j = nt * 16 + c;                           // 0..303
    int src = gate * H_SZ + j;
    f16 vals[8];
#pragma unroll
    for (int jj = 0; jj < 8; ++jj) {
        int kk = k * 32 + q * 8 + jj;
        float v = 0.f;
        if (j < H_SZ) {
            if (kk < KP) { if (kk < H_SZ) v = whh[(size_t)src * H_SZ + kk]; }
            else { int kx = kk - KP; if (kx < E_SZ) v = wih[(size_t)src * E_SZ + kx]; }
        }
        vals[jj] = (f16)v;
    }
    *(f16x8*)(Wpk + ((size_t)bid * 64 + lane) * 8) = *(const f16x8*)vals;
    if (k == 0 && q == 0)
        biasp[gate * GP + j] = (j < H_SZ) ? (bih[src] + bhh[src]) : 0.f;
}

// P2: weight-normed classifier W = g * v / ||v||  -> Wc f32 [2][GP]
__global__ void kP2(const float* __restrict__ cls_v, const float* __restrict__ cls_g,
                    float* __restrict__ Wc) {
    int lane = threadIdx.x;                        // 64
    for (int cl = 0; cl < 2; ++cl) {
        float s = 0.f;
        for (int j = lane; j < H_SZ; j += 64) { float v = cls_v[cl * H_SZ + j]; s += v * v; }
        for (int off = 32; off; off >>= 1) s += __shfl_down(s, off);
        float nrm = sqrtf(__shfl(s, 0));
        float scale = cls_g[cl] / nrm;
        for (int j = lane; j < H_SZ; j += 64) Wc[cl * GP + j] = cls_v[cl * H_SZ + j] * scale;
    }
}

// kR7: fused LSTM recurrence. 256 blocks x 1024 thr (16 waves), 16 rows/block.
// Wave (gate, n-quarter); weight stream = contiguous 1KB blocks through a 5-slot
// rotating register pipeline. __launch_bounds__(1024,4): min 4 waves/EU ->
// 128-VGPR budget (pipeline fits, no spill).
__global__ __launch_bounds__(1024, 4)
void kR7(const int* __restrict__ cap,
         const int* __restrict__ cap_len,
         const f16* __restrict__ embT,
         const f16* __restrict__ Wpk,
         const float* __restrict__ biasp,
         float* __restrict__ hlast) {
    extern __shared__ __align__(16) char smem[];
    f16*   hbuf  = (f16*)smem;                          // 16*328*2 = 10496
    f16*   xbuf  = (f16*)(smem + 10496);                // 10496
    f16*   gates = (f16*)(smem + 20992);                // 16*1224*2 = 39168
    float* biasL = (float*)(smem + 60160);              // 4864
    int*   capv  = (int*)(smem + 65024);                // 16*32*4 = 2048
    int*   lens  = (int*)(smem + 67072);                // 64
    int tid = threadIdx.x;
    int b0 = blockIdx.x * ROWS;
    if (tid < ROWS) lens[tid] = cap_len[b0 + tid];
    for (int i = tid; i < ROWS * T_SZ; i += 1024) capv[i] = cap[(size_t)b0 * T_SZ + i];
    for (int i = tid; i < ROWS * LDA; i += 1024) hbuf[i] = (f16)0.f;  // pads stay 0
    for (int i = tid; i < G4; i += 1024) biasL[i] = biasp[i];
    __syncthreads();
    // stage x for t=0
    if (tid < ROWS * 40) {
        int m = tid / 40, c8 = tid - m * 40;
        int v = capv[m * T_SZ + 0];
        *(f16x8*)(xbuf + m * LDA + c8 * 8) = *(const f16x8*)(embT + (size_t)v * KP + c8 * 8);
    }
    __syncthreads();
    int wave = tid >> 6, lane = tid & 63;
    int c = lane & 15, q = lane >> 4;
    int gate = wave >> 2, q4 = wave & 3;
    int nt0 = q4 * 5, cnt = (q4 == 3) ? 4 : 5;     // 19 = 5+5+5+4
    const f16* wp0 = Wpk + ((size_t)((gate * 19 + nt0) * 20) * 64 + lane) * 8;
    const f16* hrow = hbuf + c * LDA + q * 8;
    const f16* xrow = xbuf + c * LDA + q * 8;
    float creg[5];                                  // per-thread c-state, idx map fixed over t
#pragma unroll
    for (int i = 0; i < 5; ++i) creg[i] = 0.f;

    for (int t = 0; t < T_SZ; ++t) {
        // --- phase 1: gate preacts, K=640 fused [h|x] ---
        f16x8 afr[10];
#pragma unroll
        for (int k = 0; k < 10; ++k)
            afr[k] = *(const f16x8*)(hrow + k * 32);
        // weight pipeline prologue: slots 0..4 <- stream blocks 0..4
        f16x8 buf[5];
#pragma unroll
        for (int s = 0; s < 5; ++s)
            buf[s] = *(const f16x8*)(wp0 + (size_t)s * 512);
        // steady state: tiles 0..cnt-2, unconditional prefetch
#pragma unroll 1
        for (int nt = 0; nt < cnt - 1; ++nt) {
            int base = nt * 20;
            int ncol = gate * GP + (nt0 + nt) * 16 + c;
            float bia = biasL[ncol];
            f32x4 acc = {bia, bia, bia, bia};
#pragma unroll
            for (int k = 0; k < 20; ++k) {
                f16x8 a;
                if (k < 10) a = afr[k];
                else        a = *(const f16x8*)(xrow + (k - 10) * 32);
                acc = __builtin_amdgcn_mfma_f32_16x16x32_f16(a, buf[k % 5], acc, 0, 0, 0);
                buf[k % 5] = *(const f16x8*)(wp0 + (size_t)(base + k + 5) * 512);
            }
#pragma unroll
            for (int r = 0; r < 4; ++r)
                gates[(q * 4 + r) * LDG + ncol] = (f16)acc[r];
        }
        // final tile (nt = cnt-1): prefetch only while stream remains (k<15)
        {
            int nt = cnt - 1;
            int base = nt * 20;
            int ncol = gate * GP + (nt0 + nt) * 16 + c;
            float bia = biasL[ncol];
            f32x4 acc = {bia, bia, bia, bia};
#pragma unroll
            for (int k = 0; k < 20; ++k) {
                f16x8 a;
                if (k < 10) a = afr[k];
                else        a = *(const f16x8*)(xrow + (k - 10) * 32);
                acc = __builtin_amdgcn_mfma_f32_16x16x32_f16(a, buf[k % 5], acc, 0, 0, 0);
                if (k < 15)
                    buf[k % 5] = *(const f16x8*)(wp0 + (size_t)(base + k + 5) * 512);
            }
#pragma unroll
            for (int r = 0; r < 4; ++r)
                gates[(q * 4 + r) * LDG + ncol] = (f16)acc[r];
        }
        __syncthreads();
        // --- phase 2: elementwise cell update + stage x(t+1) ---
        int tp1 = t + 1;
        if (tp1 < T_SZ && tid < ROWS * 40) {
            int m = tid / 40, c8 = tid - m * 40;
            int v = capv[m * T_SZ + tp1];
            *(f16x8*)(xbuf + m * LDA + c8 * 8) = *(const f16x8*)(embT + (size_t)v * KP + c8 * 8);
        }
#pragma unroll
        for (int it = 0; it < 5; ++it) {
            int idx = tid + it * 1024;             // 0..5119 = 16*320
            int m = idx / 320, j = idx - m * 320;
            if (j < H_SZ) {
                const f16* gr = gates + m * LDG;
                float gi = (float)gr[j];
                float gf = (float)gr[GP + j];
                float gg = (float)gr[2 * GP + j];
                float go = (float)gr[3 * GP + j];
                float ii = sigmoid_f(gi);
                float ff = sigmoid_f(gf);
                float gt = tanh_f(gg);
                float oo = sigmoid_f(go);
                float cn = ff * creg[it] + ii * gt;
                creg[it] = cn;
                float hh = oo * tanh_f(cn);
                hbuf[m * LDA + j] = (f16)hh;
                if (t == lens[m] - 1) hlast[(size_t)(b0 + m) * GP + j] = hh;
            }
        }
        __syncthreads();
    }
}

// kC: out[row][cl] = hlast[row] . Wc[cl] + cls_b[cl]
__global__ void kC(const float* __restrict__ hlast, const float* __restrict__ Wc,
                   const float* __restrict__ cls_b, float* __restrict__ out) {
    int row = blockIdx.x, lane = threadIdx.x;      // 64 threads
    const float* h = hlast + (size_t)row * GP;
    float s0 = 0.f, s1 = 0.f;
    for (int j = lane; j < H_SZ; j += 64) {
        float hv = h[j];
        s0 += hv * Wc[j];
        s1 += hv * Wc[GP + j];
    }
    for (int off = 32; off; off >>= 1) {
        s0 += __shfl_down(s0, off);
        s1 += __shfl_down(s1, off);
    }
    if (lane == 0) {
        out[row * 2 + 0] = s0 + cls_b[0];
        out[row * 2 + 1] = s1 + cls_b[1];
    }
}

extern "C" void kernel_launch(void* const* d_in, const int* in_sizes, int n_in,
                              void* d_out, int out_size, void* d_ws, size_t ws_size,
                              hipStream_t stream) {
    const int*   cap     = (const int*)d_in[0];
    const int*   cap_len = (const int*)d_in[1];
    const float* embed_w = (const float*)d_in[2];
    const float* W_ih    = (const float*)d_in[3];
    const float* W_hh    = (const float*)d_in[4];
    const float* b_ih    = (const float*)d_in[5];
    const float* b_hh    = (const float*)d_in[6];
    const float* cls_v   = (const float*)d_in[7];
    const float* cls_g   = (const float*)d_in[8];
    const float* cls_b   = (const float*)d_in[9];
    float* out = (float*)d_out;

    char* w = (char*)d_ws;
    size_t off = 0;
    auto alloc = [&](size_t bytes) -> void* {
        void* p = w + off;
        off += (bytes + 255) & ~(size_t)255;
        return p;
    };
    f16*   embT  = (f16*)alloc((size_t)VOCAB * KP * sizeof(f16));      // 6.4 MB
    f16*   Wpk   = (f16*)alloc((size_t)1520 * 64 * 8 * sizeof(f16));   // 1.56 MB
    float* biasp = (float*)alloc((size_t)G4 * sizeof(float));
    float* Wc    = (float*)alloc((size_t)2 * GP * sizeof(float));
    float* hlast = (float*)alloc((size_t)B_SZ * GP * sizeof(float));   // 5.0 MB

    // dynamic LDS: 67,136 B. Host-side config op, capture-safe.
    static const int smem_bytes = 67072 + 64;
    (void)hipFuncSetAttribute((const void*)kR7,
                              hipFuncAttributeMaxDynamicSharedMemorySize, smem_bytes);

    kP0<<<VOCAB, KP, 0, stream>>>(embed_w, embT);
    kPW2<<<1520, 64, 0, stream>>>(W_ih, W_hh, b_ih, b_hh, Wpk, biasp);
    kP2<<<1, 64, 0, stream>>>(cls_v, cls_g, Wc);
    kR7<<<NBLK, 1024, smem_bytes, stream>>>(cap, cap_len, embT, Wpk, biasp, hlast);
    kC<<<B_SZ, 64, 0, stream>>>(hlast, Wc, cls_b, out);
}

// Round 9
// 600.337 us; speedup vs baseline: 1.6910x; 1.6910x over previous
//
#include <hip/hip_runtime.h>
#include <hip/hip_fp16.h>

typedef _Float16 f16;
typedef _Float16 f16x8 __attribute__((ext_vector_type(8)));
typedef float f32x4 __attribute__((ext_vector_type(4)));

#define B_SZ   4096
#define T_SZ   32
#define VOCAB  10000
#define E_SZ   300
#define H_SZ   300
#define KP     320          // embT row width (10x32)
#define GP     304          // per-gate padded N (19x16)
#define G4     1216         // 4*GP
#define LDA    328          // hbuf/xbuf row stride f16 (16B-aligned rows)
#define LDG    1224         // gates row stride f16
#define ROWS   16           // batch rows per block
#define NBLK   (B_SZ/ROWS)  // 256 blocks -> 1 per CU

__device__ __forceinline__ float sigmoid_f(float x) {
    return 1.f / (1.f + __expf(-x));
}
__device__ __forceinline__ float tanh_f(float x) {
    x = fminf(fmaxf(x, -15.f), 15.f);
    float e = __expf(2.f * x);
    return (e - 1.f) / (e + 1.f);
}

// P0: embed_w f32 [V][300] -> embT f16 [V][320] zero-padded
__global__ void kP0(const float* __restrict__ ew, f16* __restrict__ embT) {
    int v = blockIdx.x, k = threadIdx.x;           // 320 threads
    embT[(size_t)v * KP + k] = (k < E_SZ) ? (f16)ew[(size_t)v * E_SZ + k] : (f16)0.f;
}

// kPW2: pack weights into MFMA-B-fragment order, coalesced.
// Wpk block (gate,nt,k) = 1024 B; lane (c,q) holds W[n=gate*300+nt*16+c][kk=k*32+q*8..+7]
// kk<320 -> W_hh col kk, kk>=320 -> W_ih col kk-320 (zero-padded).
__global__ void kPW2(const float* __restrict__ wih, const float* __restrict__ whh,
                     const float* __restrict__ bih, const float* __restrict__ bhh,
                     f16* __restrict__ Wpk, float* __restrict__ biasp) {
    int bid = blockIdx.x;                          // 0..1519 = (gate*19+nt)*20+k
    int lane = threadIdx.x;                        // 64
    int k = bid % 20, ntg = bid / 20;
    int nt = ntg % 19, gate = ntg / 19;
    int c = lane & 15, q = lane >> 4;
    int j = nt * 16 + c;                           // 0..303
    int src = gate * H_SZ + j;
    f16 vals[8];
#pragma unroll
    for (int jj = 0; jj < 8; ++jj) {
        int kk = k * 32 + q * 8 + jj;
        float v = 0.f;
        if (j < H_SZ) {
            if (kk < KP) { if (kk < H_SZ) v = whh[(size_t)src * H_SZ + kk]; }
            else { int kx = kk - KP; if (kx < E_SZ) v = wih[(size_t)src * E_SZ + kx]; }
        }
        vals[jj] = (f16)v;
    }
    *(f16x8*)(Wpk + ((size_t)bid * 64 + lane) * 8) = *(const f16x8*)vals;
    if (k == 0 && q == 0)
        biasp[gate * GP + j] = (j < H_SZ) ? (bih[src] + bhh[src]) : 0.f;
}

// P2: weight-normed classifier W = g * v / ||v||  -> Wc f32 [2][GP]
__global__ void kP2(const float* __restrict__ cls_v, const float* __restrict__ cls_g,
                    float* __restrict__ Wc) {
    int lane = threadIdx.x;                        // 64
    for (int cl = 0; cl < 2; ++cl) {
        float s = 0.f;
        for (int j = lane; j < H_SZ; j += 64) { float v = cls_v[cl * H_SZ + j]; s += v * v; }
        for (int off = 32; off; off >>= 1) s += __shfl_down(s, off);
        float nrm = sqrtf(__shfl(s, 0));
        float scale = cls_g[cl] / nrm;
        for (int j = lane; j < H_SZ; j += 64) Wc[cl * GP + j] = cls_v[cl * H_SZ + j] * scale;
    }
}

// kR8: fused LSTM recurrence. 256 blocks x 512 thr (8 waves), 16 rows/block.
// Wave (gate = w>>1, half = w&1): 10 or 9 nt-tiles of one gate.
// 512-thread shape => compiler targets 128 VGPRs (proven R3/R4, no spill).
// 10-slot rotating register pipeline on the contiguous packed weight stream.
__global__ __launch_bounds__(512, 2)
void kR8(const int* __restrict__ cap,
         const int* __restrict__ cap_len,
         const f16* __restrict__ embT,
         const f16* __restrict__ Wpk,
         const float* __restrict__ biasp,
         float* __restrict__ hlast) {
    extern __shared__ __align__(16) char smem[];
    f16*   hbuf  = (f16*)smem;                          // 16*328*2 = 10496
    f16*   xbuf  = (f16*)(smem + 10496);                // 10496
    f16*   gates = (f16*)(smem + 20992);                // 16*1224*2 = 39168
    float* biasL = (float*)(smem + 60160);              // 4864
    int*   capv  = (int*)(smem + 65024);                // 16*32*4 = 2048
    int*   lens  = (int*)(smem + 67072);                // 64
    int tid = threadIdx.x;
    int b0 = blockIdx.x * ROWS;
    if (tid < ROWS) lens[tid] = cap_len[b0 + tid];
    for (int i = tid; i < ROWS * T_SZ; i += 512) capv[i] = cap[(size_t)b0 * T_SZ + i];
    for (int i = tid; i < ROWS * LDA; i += 512) hbuf[i] = (f16)0.f;  // pads stay 0
    for (int i = tid; i < G4; i += 512) biasL[i] = biasp[i];
    __syncthreads();
    // stage x for t=0 (640 chunks of 8 f16)
    for (int i = tid; i < ROWS * 40; i += 512) {
        int m = i / 40, c8 = i - m * 40;
        int v = capv[m * T_SZ + 0];
        *(f16x8*)(xbuf + m * LDA + c8 * 8) = *(const f16x8*)(embT + (size_t)v * KP + c8 * 8);
    }
    __syncthreads();
    int wave = tid >> 6, lane = tid & 63;
    int c = lane & 15, q = lane >> 4;
    int gate = wave >> 1, half = wave & 1;
    int nt0 = half * 10, ntiles = half ? 9 : 10;   // 19 = 10 + 9
    const f16* wp0 = Wpk + ((size_t)((gate * 19 + nt0) * 20) * 64 + lane) * 8;
    const f16* hrow = hbuf + c * LDA + q * 8;
    const f16* xrow = xbuf + c * LDA + q * 8;
    float creg[10];                                 // per-thread c-state, idx map fixed over t
#pragma unroll
    for (int i = 0; i < 10; ++i) creg[i] = 0.f;

    for (int t = 0; t < T_SZ; ++t) {
        // --- phase 1: gate preacts, K=640 fused [h|x] ---
        f16x8 afr[10];
#pragma unroll
        for (int k = 0; k < 10; ++k)
            afr[k] = *(const f16x8*)(hrow + k * 32);
        // weight pipeline prologue: slots 0..9 <- stream blocks 0..9
        f16x8 buf[10];
#pragma unroll
        for (int s = 0; s < 10; ++s)
            buf[s] = *(const f16x8*)(wp0 + (size_t)s * 512);
        // steady state: tiles 0..ntiles-2, unconditional prefetch distance 10
#pragma unroll 1
        for (int nt = 0; nt < ntiles - 1; ++nt) {
            int base = nt * 20;
            int ncol = gate * GP + (nt0 + nt) * 16 + c;
            float bia = biasL[ncol];
            f32x4 acch = {bia, bia, bia, bia};
            f32x4 accx = {0.f, 0.f, 0.f, 0.f};
#pragma unroll
            for (int k = 0; k < 20; ++k) {
                if (k < 10) {
                    acch = __builtin_amdgcn_mfma_f32_16x16x32_f16(afr[k], buf[k % 10], acch, 0, 0, 0);
                } else {
                    f16x8 a = *(const f16x8*)(xrow + (k - 10) * 32);
                    accx = __builtin_amdgcn_mfma_f32_16x16x32_f16(a, buf[k % 10], accx, 0, 0, 0);
                }
                buf[k % 10] = *(const f16x8*)(wp0 + (size_t)(base + k + 10) * 512);
            }
#pragma unroll
            for (int r = 0; r < 4; ++r)
                gates[(q * 4 + r) * LDG + ncol] = (f16)(acch[r] + accx[r]);
        }
        // final tile: prefetch only while stream remains (k < 10)
        {
            int nt = ntiles - 1;
            int base = nt * 20;
            int ncol = gate * GP + (nt0 + nt) * 16 + c;
            float bia = biasL[ncol];
            f32x4 acch = {bia, bia, bia, bia};
            f32x4 accx = {0.f, 0.f, 0.f, 0.f};
#pragma unroll
            for (int k = 0; k < 20; ++k) {
                if (k < 10) {
                    acch = __builtin_amdgcn_mfma_f32_16x16x32_f16(afr[k], buf[k % 10], acch, 0, 0, 0);
                    buf[k % 10] = *(const f16x8*)(wp0 + (size_t)(base + k + 10) * 512);
                } else {
                    f16x8 a = *(const f16x8*)(xrow + (k - 10) * 32);
                    accx = __builtin_amdgcn_mfma_f32_16x16x32_f16(a, buf[k % 10], accx, 0, 0, 0);
                }
            }
#pragma unroll
            for (int r = 0; r < 4; ++r)
                gates[(q * 4 + r) * LDG + ncol] = (f16)(acch[r] + accx[r]);
        }
        __syncthreads();
        // --- phase 2: elementwise cell update + stage x(t+1) ---
        int tp1 = t + 1;
        if (tp1 < T_SZ) {
            for (int i = tid; i < ROWS * 40; i += 512) {
                int m = i / 40, c8 = i - m * 40;
                int v = capv[m * T_SZ + tp1];
                *(f16x8*)(xbuf + m * LDA + c8 * 8) =
                    *(const f16x8*)(embT + (size_t)v * KP + c8 * 8);
            }
        }
#pragma unroll
        for (int it = 0; it < 10; ++it) {
            int idx = tid + it * 512;              // 0..5119 = 16*320
            int m = idx / 320, j = idx - m * 320;
            if (j < H_SZ) {
                const f16* gr = gates + m * LDG;
                float gi = (float)gr[j];
                float gf = (float)gr[GP + j];
                float gg = (float)gr[2 * GP + j];
                float go = (float)gr[3 * GP + j];
                float ii = sigmoid_f(gi);
                float ff = sigmoid_f(gf);
                float gt = tanh_f(gg);
                float oo = sigmoid_f(go);
                float cn = ff * creg[it] + ii * gt;
                creg[it] = cn;
                float hh = oo * tanh_f(cn);
                hbuf[m * LDA + j] = (f16)hh;
                if (t == lens[m] - 1) hlast[(size_t)(b0 + m) * GP + j] = hh;
            }
        }
        __syncthreads();
    }
}

// kC: out[row][cl] = hlast[row] . Wc[cl] + cls_b[cl]
__global__ void kC(const float* __restrict__ hlast, const float* __restrict__ Wc,
                   const float* __restrict__ cls_b, float* __restrict__ out) {
    int row = blockIdx.x, lane = threadIdx.x;      // 64 threads
    const float* h = hlast + (size_t)row * GP;
    float s0 = 0.f, s1 = 0.f;
    for (int j = lane; j < H_SZ; j += 64) {
        float hv = h[j];
        s0 += hv * Wc[j];
        s1 += hv * Wc[GP + j];
    }
    for (int off = 32; off; off >>= 1) {
        s0 += __shfl_down(s0, off);
        s1 += __shfl_down(s1, off);
    }
    if (lane == 0) {
        out[row * 2 + 0] = s0 + cls_b[0];
        out[row * 2 + 1] = s1 + cls_b[1];
    }
}

extern "C" void kernel_launch(void* const* d_in, const int* in_sizes, int n_in,
                              void* d_out, int out_size, void* d_ws, size_t ws_size,
                              hipStream_t stream) {
    const int*   cap     = (const int*)d_in[0];
    const int*   cap_len = (const int*)d_in[1];
    const float* embed_w = (const float*)d_in[2];
    const float* W_ih    = (const float*)d_in[3];
    const float* W_hh    = (const float*)d_in[4];
    const float* b_ih    = (const float*)d_in[5];
    const float* b_hh    = (const float*)d_in[6];
    const float* cls_v   = (const float*)d_in[7];
    const float* cls_g   = (const float*)d_in[8];
    const float* cls_b   = (const float*)d_in[9];
    float* out = (float*)d_out;

    char* w = (char*)d_ws;
    size_t off = 0;
    auto alloc = [&](size_t bytes) -> void* {
        void* p = w + off;
        off += (bytes + 255) & ~(size_t)255;
        return p;
    };
    f16*   embT  = (f16*)alloc((size_t)VOCAB * KP * sizeof(f16));      // 6.4 MB
    f16*   Wpk   = (f16*)alloc((size_t)1520 * 64 * 8 * sizeof(f16));   // 1.56 MB
    float* biasp = (float*)alloc((size_t)G4 * sizeof(float));
    float* Wc    = (float*)alloc((size_t)2 * GP * sizeof(float));
    float* hlast = (float*)alloc((size_t)B_SZ * GP * sizeof(float));   // 5.0 MB

    // dynamic LDS: 67,136 B. Host-side config op, capture-safe.
    static const int smem_bytes = 67072 + 64;
    (void)hipFuncSetAttribute((const void*)kR8,
                              hipFuncAttributeMaxDynamicSharedMemorySize, smem_bytes);

    kP0<<<VOCAB, KP, 0, stream>>>(embed_w, embT);
    kPW2<<<1520, 64, 0, stream>>>(W_ih, W_hh, b_ih, b_hh, Wpk, biasp);
    kP2<<<1, 64, 0, stream>>>(cls_v, cls_g, Wc);
    kR8<<<NBLK, 512, smem_bytes, stream>>>(cap, cap_len, embT, Wpk, biasp, hlast);
    kC<<<B_SZ, 64, 0, stream>>>(hlast, Wc, cls_b, out);
}

// Round 10
// 490.028 us; speedup vs baseline: 2.0717x; 1.2251x over previous
//
#include <hip/hip_runtime.h>
#include <hip/hip_fp16.h>

typedef _Float16 f16;
typedef _Float16 f16x8 __attribute__((ext_vector_type(8)));
typedef float f32x4 __attribute__((ext_vector_type(4)));

#define B_SZ   4096
#define T_SZ   32
#define VOCAB  10000
#define E_SZ   300
#define H_SZ   300
#define KP     320          // embT row width (10x32)
#define GP     304          // per-gate padded N (19x16)
#define G4     1216         // 4*GP
#define LDA    328          // hbuf/xbuf row stride f16 (16B-aligned rows)
#define LDG    1224         // gates row stride f16
#define ROWS   16           // batch rows per block
#define NBLK   (B_SZ/ROWS)  // 256 blocks -> 1 per CU

__device__ __forceinline__ float sigmoid_f(float x) {
    return 1.f / (1.f + __expf(-x));
}
__device__ __forceinline__ float tanh_f(float x) {
    x = fminf(fmaxf(x, -15.f), 15.f);
    float e = __expf(2.f * x);
    return (e - 1.f) / (e + 1.f);
}

// P0: embed_w f32 [V][300] -> embT f16 [V][320] zero-padded
__global__ void kP0(const float* __restrict__ ew, f16* __restrict__ embT) {
    int v = blockIdx.x, k = threadIdx.x;           // 320 threads
    embT[(size_t)v * KP + k] = (k < E_SZ) ? (f16)ew[(size_t)v * E_SZ + k] : (f16)0.f;
}

// kPW2: pack weights into MFMA-B-fragment order, coalesced.
// Wpk block (gate,nt,k) = 1024 B; lane (c,q) holds W[n=gate*300+nt*16+c][kk=k*32+q*8..+7]
// kk<320 -> W_hh col kk, kk>=320 -> W_ih col kk-320 (zero-padded).
__global__ void kPW2(const float* __restrict__ wih, const float* __restrict__ whh,
                     const float* __restrict__ bih, const float* __restrict__ bhh,
                     f16* __restrict__ Wpk, float* __restrict__ biasp) {
    int bid = blockIdx.x;                          // 0..1519 = (gate*19+nt)*20+k
    int lane = threadIdx.x;                        // 64
    int k = bid % 20, ntg = bid / 20;
    int nt = ntg % 19, gate = ntg / 19;
    int c = lane & 15, q = lane >> 4;
    int j = nt * 16 + c;                           // 0..303
    int src = gate * H_SZ + j;
    f16 vals[8];
#pragma unroll
    for (int jj = 0; jj < 8; ++jj) {
        int kk = k * 32 + q * 8 + jj;
        float v = 0.f;
        if (j < H_SZ) {
            if (kk < KP) { if (kk < H_SZ) v = whh[(size_t)src * H_SZ + kk]; }
            else { int kx = kk - KP; if (kx < E_SZ) v = wih[(size_t)src * E_SZ + kx]; }
        }
        vals[jj] = (f16)v;
    }
    *(f16x8*)(Wpk + ((size_t)bid * 64 + lane) * 8) = *(const f16x8*)vals;
    if (k == 0 && q == 0)
        biasp[gate * GP + j] = (j < H_SZ) ? (bih[src] + bhh[src]) : 0.f;
}

// P2: weight-normed classifier W = g * v / ||v||  -> Wc f32 [2][GP]
__global__ void kP2(const float* __restrict__ cls_v, const float* __restrict__ cls_g,
                    float* __restrict__ Wc) {
    int lane = threadIdx.x;                        // 64
    for (int cl = 0; cl < 2; ++cl) {
        float s = 0.f;
        for (int j = lane; j < H_SZ; j += 64) { float v = cls_v[cl * H_SZ + j]; s += v * v; }
        for (int off = 32; off; off >>= 1) s += __shfl_down(s, off);
        float nrm = sqrtf(__shfl(s, 0));
        float scale = cls_g[cl] / nrm;
        for (int j = lane; j < H_SZ; j += 64) Wc[cl * GP + j] = cls_v[cl * H_SZ + j] * scale;
    }
}

// kX: per-vocab x-gate preacts embG[v][1216] = W_ih . emb[v] + (b_ih+b_hh), f32.
// 625 blocks x 512 thr; block = 16 vocab rows; wave (gate, half) streams its
// gate's W_ih blocks (k in [10,20) of each 20-block group) via 10-slot pipeline.
__global__ __launch_bounds__(512, 2)
void kX(const f16* __restrict__ embT, const f16* __restrict__ Wpk,
        const float* __restrict__ biasp, float* __restrict__ embG) {
    int tid = threadIdx.x;
    int v0 = blockIdx.x * 16;
    int wave = tid >> 6, lane = tid & 63;
    int c = lane & 15, q = lane >> 4;
    int gate = wave >> 1, half = wave & 1;
    int nt0 = half * 10, ntiles = half ? 9 : 10;   // 19 = 10 + 9
    const f16* wp0 = Wpk + (((size_t)(gate * 19 + nt0) * 20 + 10) * 64 + lane) * 8;
    f16x8 afr[10];
    const f16* arow = embT + (size_t)(v0 + c) * KP + q * 8;
#pragma unroll
    for (int k = 0; k < 10; ++k)
        afr[k] = *(const f16x8*)(arow + k * 32);
    f16x8 buf[10];
#pragma unroll
    for (int s = 0; s < 10; ++s)
        buf[s] = *(const f16x8*)(wp0 + (size_t)s * 512);
#pragma unroll 1
    for (int nt = 0; nt < ntiles - 1; ++nt) {
        int ncol = gate * GP + (nt0 + nt) * 16 + c;
        float bia = biasp[ncol];
        f32x4 acc = {bia, bia, bia, bia};
#pragma unroll
        for (int k = 0; k < 10; ++k) {
            acc = __builtin_amdgcn_mfma_f32_16x16x32_f16(afr[k], buf[k], acc, 0, 0, 0);
            buf[k] = *(const f16x8*)(wp0 + (size_t)(nt * 20 + k + 20) * 512);
        }
#pragma unroll
        for (int r = 0; r < 4; ++r)
            embG[(size_t)(v0 + q * 4 + r) * G4 + ncol] = acc[r];
    }
    {
        int nt = ntiles - 1;
        int ncol = gate * GP + (nt0 + nt) * 16 + c;
        float bia = biasp[ncol];
        f32x4 acc = {bia, bia, bia, bia};
#pragma unroll
        for (int k = 0; k < 10; ++k)
            acc = __builtin_amdgcn_mfma_f32_16x16x32_f16(afr[k], buf[k], acc, 0, 0, 0);
#pragma unroll
        for (int r = 0; r < 4; ++r)
            embG[(size_t)(v0 + q * 4 + r) * G4 + ncol] = acc[r];
    }
}

// kR9: W_hh-only recurrence. 256 blocks x 512 thr (8 waves), 16 rows/block.
// Wave (gate, half): 10/9 nt-tiles, K=320 (h only). x-preacts gathered from
// embG (f32, per-token) in phase 2. Weight stream = 760 KB/step/CU (half of fused).
__global__ __launch_bounds__(512, 2)
void kR9(const int* __restrict__ cap,
         const int* __restrict__ cap_len,
         const float* __restrict__ embG,
         const f16* __restrict__ Wpk,
         float* __restrict__ hlast) {
    __shared__ __align__(16) f16 hbuf[ROWS * LDA];      // 10496 B
    __shared__ __align__(16) f16 gates[ROWS * LDG];     // 39168 B
    __shared__ int capv[ROWS * T_SZ];                   // 2048 B
    __shared__ int lens[ROWS];                          // 64 B
    int tid = threadIdx.x;
    int b0 = blockIdx.x * ROWS;
    if (tid < ROWS) lens[tid] = cap_len[b0 + tid];
    for (int i = tid; i < ROWS * T_SZ; i += 512) capv[i] = cap[(size_t)b0 * T_SZ + i];
    for (int i = tid; i < ROWS * LDA; i += 512) hbuf[i] = (f16)0.f;  // pads stay 0
    __syncthreads();
    int wave = tid >> 6, lane = tid & 63;
    int c = lane & 15, q = lane >> 4;
    int gate = wave >> 1, half = wave & 1;
    int nt0 = half * 10, ntiles = half ? 9 : 10;   // 19 = 10 + 9
    const f16* wp0 = Wpk + ((size_t)((gate * 19 + nt0) * 20) * 64 + lane) * 8;  // W_hh blocks
    const f16* hrow = hbuf + c * LDA + q * 8;
    float creg[10];                                 // per-thread c-state, idx map fixed over t
#pragma unroll
    for (int i = 0; i < 10; ++i) creg[i] = 0.f;

    for (int t = 0; t < T_SZ; ++t) {
        // --- phase 1: h-preacts = h @ W_hh^T, 10-slot pipelined weight stream ---
        f16x8 afr[10];
#pragma unroll
        for (int k = 0; k < 10; ++k)
            afr[k] = *(const f16x8*)(hrow + k * 32);
        f16x8 buf[10];
#pragma unroll
        for (int s = 0; s < 10; ++s)
            buf[s] = *(const f16x8*)(wp0 + (size_t)s * 512);
#pragma unroll 1
        for (int nt = 0; nt < ntiles - 1; ++nt) {
            int ncol = gate * GP + (nt0 + nt) * 16 + c;
            f32x4 acc = {0.f, 0.f, 0.f, 0.f};
#pragma unroll
            for (int k = 0; k < 10; ++k) {
                acc = __builtin_amdgcn_mfma_f32_16x16x32_f16(afr[k], buf[k], acc, 0, 0, 0);
                buf[k] = *(const f16x8*)(wp0 + (size_t)(nt * 20 + k + 20) * 512);
            }
#pragma unroll
            for (int r = 0; r < 4; ++r)
                gates[(q * 4 + r) * LDG + ncol] = (f16)acc[r];
        }
        {
            int nt = ntiles - 1;
            int ncol = gate * GP + (nt0 + nt) * 16 + c;
            f32x4 acc = {0.f, 0.f, 0.f, 0.f};
#pragma unroll
            for (int k = 0; k < 10; ++k)
                acc = __builtin_amdgcn_mfma_f32_16x16x32_f16(afr[k], buf[k], acc, 0, 0, 0);
#pragma unroll
            for (int r = 0; r < 4; ++r)
                gates[(q * 4 + r) * LDG + ncol] = (f16)acc[r];
        }
        __syncthreads();
        // --- phase 2: cell update; x-preacts gathered from embG (L2) ---
#pragma unroll
        for (int it = 0; it < 10; ++it) {
            int idx = tid + it * 512;              // 0..5119 = 16*320
            int m = idx / 320, j = idx - m * 320;
            if (j < H_SZ) {
                int v = capv[m * T_SZ + t];
                const float* xr = embG + (size_t)v * G4;
                const f16* gr = gates + m * LDG;
                float gi = (float)gr[j]          + xr[j];
                float gf = (float)gr[GP + j]     + xr[GP + j];
                float gg = (float)gr[2 * GP + j] + xr[2 * GP + j];
                float go = (float)gr[3 * GP + j] + xr[3 * GP + j];
                float ii = sigmoid_f(gi);
                float ff = sigmoid_f(gf);
                float gt = tanh_f(gg);
                float oo = sigmoid_f(go);
                float cn = ff * creg[it] + ii * gt;
                creg[it] = cn;
                float hh = oo * tanh_f(cn);
                hbuf[m * LDA + j] = (f16)hh;
                if (t == lens[m] - 1) hlast[(size_t)(b0 + m) * GP + j] = hh;
            }
        }
        __syncthreads();
    }
}

// kR8 (fallback, proven 584 us): fused [h|x] recurrence, used when ws too small for embG.
__global__ __launch_bounds__(512, 2)
void kR8(const int* __restrict__ cap,
         const int* __restrict__ cap_len,
         const f16* __restrict__ embT,
         const f16* __restrict__ Wpk,
         const float* __restrict__ biasp,
         float* __restrict__ hlast) {
    extern __shared__ __align__(16) char smem[];
    f16*   hbuf  = (f16*)smem;                          // 10496
    f16*   xbuf  = (f16*)(smem + 10496);                // 10496
    f16*   gates = (f16*)(smem + 20992);                // 39168
    float* biasL = (float*)(smem + 60160);              // 4864
    int*   capv  = (int*)(smem + 65024);                // 2048
    int*   lens  = (int*)(smem + 67072);                // 64
    int tid = threadIdx.x;
    int b0 = blockIdx.x * ROWS;
    if (tid < ROWS) lens[tid] = cap_len[b0 + tid];
    for (int i = tid; i < ROWS * T_SZ; i += 512) capv[i] = cap[(size_t)b0 * T_SZ + i];
    for (int i = tid; i < ROWS * LDA; i += 512) hbuf[i] = (f16)0.f;
    for (int i = tid; i < G4; i += 512) biasL[i] = biasp[i];
    __syncthreads();
    for (int i = tid; i < ROWS * 40; i += 512) {
        int m = i / 40, c8 = i - m * 40;
        int v = capv[m * T_SZ + 0];
        *(f16x8*)(xbuf + m * LDA + c8 * 8) = *(const f16x8*)(embT + (size_t)v * KP + c8 * 8);
    }
    __syncthreads();
    int wave = tid >> 6, lane = tid & 63;
    int c = lane & 15, q = lane >> 4;
    int gate = wave >> 1, half = wave & 1;
    int nt0 = half * 10, ntiles = half ? 9 : 10;
    const f16* wp0 = Wpk + ((size_t)((gate * 19 + nt0) * 20) * 64 + lane) * 8;
    const f16* hrow = hbuf + c * LDA + q * 8;
    const f16* xrow = xbuf + c * LDA + q * 8;
    float creg[10];
#pragma unroll
    for (int i = 0; i < 10; ++i) creg[i] = 0.f;

    for (int t = 0; t < T_SZ; ++t) {
        f16x8 afr[10];
#pragma unroll
        for (int k = 0; k < 10; ++k)
            afr[k] = *(const f16x8*)(hrow + k * 32);
        f16x8 buf[10];
#pragma unroll
        for (int s = 0; s < 10; ++s)
            buf[s] = *(const f16x8*)(wp0 + (size_t)s * 512);
#pragma unroll 1
        for (int nt = 0; nt < ntiles - 1; ++nt) {
            int base = nt * 20;
            int ncol = gate * GP + (nt0 + nt) * 16 + c;
            float bia = biasL[ncol];
            f32x4 acch = {bia, bia, bia, bia};
            f32x4 accx = {0.f, 0.f, 0.f, 0.f};
#pragma unroll
            for (int k = 0; k < 20; ++k) {
                if (k < 10) {
                    acch = __builtin_amdgcn_mfma_f32_16x16x32_f16(afr[k], buf[k % 10], acch, 0, 0, 0);
                } else {
                    f16x8 a = *(const f16x8*)(xrow + (k - 10) * 32);
                    accx = __builtin_amdgcn_mfma_f32_16x16x32_f16(a, buf[k % 10], accx, 0, 0, 0);
                }
                buf[k % 10] = *(const f16x8*)(wp0 + (size_t)(base + k + 10) * 512);
            }
#pragma unroll
            for (int r = 0; r < 4; ++r)
                gates[(q * 4 + r) * LDG + ncol] = (f16)(acch[r] + accx[r]);
        }
        {
            int nt = ntiles - 1;
            int base = nt * 20;
            int ncol = gate * GP + (nt0 + nt) * 16 + c;
            float bia = biasL[ncol];
            f32x4 acch = {bia, bia, bia, bia};
            f32x4 accx = {0.f, 0.f, 0.f, 0.f};
#pragma unroll
            for (int k = 0; k < 20; ++k) {
                if (k < 10) {
                    acch = __builtin_amdgcn_mfma_f32_16x16x32_f16(afr[k], buf[k % 10], acch, 0, 0, 0);
                    buf[k % 10] = *(const f16x8*)(wp0 + (size_t)(base + k + 10) * 512);
                } else {
                    f16x8 a = *(const f16x8*)(xrow + (k - 10) * 32);
                    accx = __builtin_amdgcn_mfma_f32_16x16x32_f16(a, buf[k % 10], accx, 0, 0, 0);
                }
            }
#pragma unroll
            for (int r = 0; r < 4; ++r)
                gates[(q * 4 + r) * LDG + ncol] = (f16)(acch[r] + accx[r]);
        }
        __syncthreads();
        int tp1 = t + 1;
        if (tp1 < T_SZ) {
            for (int i = tid; i < ROWS * 40; i += 512) {
                int m = i / 40, c8 = i - m * 40;
                int v = capv[m * T_SZ + tp1];
                *(f16x8*)(xbuf + m * LDA + c8 * 8) =
                    *(const f16x8*)(embT + (size_t)v * KP + c8 * 8);
            }
        }
#pragma unroll
        for (int it = 0; it < 10; ++it) {
            int idx = tid + it * 512;
            int m = idx / 320, j = idx - m * 320;
            if (j < H_SZ) {
                const f16* gr = gates + m * LDG;
                float gi = (float)gr[j];
                float gf = (float)gr[GP + j];
                float gg = (float)gr[2 * GP + j];
                float go = (float)gr[3 * GP + j];
                float ii = sigmoid_f(gi);
                float ff = sigmoid_f(gf);
                float gt = tanh_f(gg);
                float oo = sigmoid_f(go);
                float cn = ff * creg[it] + ii * gt;
                creg[it] = cn;
                float hh = oo * tanh_f(cn);
                hbuf[m * LDA + j] = (f16)hh;
                if (t == lens[m] - 1) hlast[(size_t)(b0 + m) * GP + j] = hh;
            }
        }
        __syncthreads();
    }
}

// kC: out[row][cl] = hlast[row] . Wc[cl] + cls_b[cl]
__global__ void kC(const float* __restrict__ hlast, const float* __restrict__ Wc,
                   const float* __restrict__ cls_b, float* __restrict__ out) {
    int row = blockIdx.x, lane = threadIdx.x;      // 64 threads
    const float* h = hlast + (size_t)row * GP;
    float s0 = 0.f, s1 = 0.f;
    for (int j = lane; j < H_SZ; j += 64) {
        float hv = h[j];
        s0 += hv * Wc[j];
        s1 += hv * Wc[GP + j];
    }
    for (int off = 32; off; off >>= 1) {
        s0 += __shfl_down(s0, off);
        s1 += __shfl_down(s1, off);
    }
    if (lane == 0) {
        out[row * 2 + 0] = s0 + cls_b[0];
        out[row * 2 + 1] = s1 + cls_b[1];
    }
}

extern "C" void kernel_launch(void* const* d_in, const int* in_sizes, int n_in,
                              void* d_out, int out_size, void* d_ws, size_t ws_size,
                              hipStream_t stream) {
    const int*   cap     = (const int*)d_in[0];
    const int*   cap_len = (const int*)d_in[1];
    const float* embed_w = (const float*)d_in[2];
    const float* W_ih    = (const float*)d_in[3];
    const float* W_hh    = (const float*)d_in[4];
    const float* b_ih    = (const float*)d_in[5];
    const float* b_hh    = (const float*)d_in[6];
    const float* cls_v   = (const float*)d_in[7];
    const float* cls_g   = (const float*)d_in[8];
    const float* cls_b   = (const float*)d_in[9];
    float* out = (float*)d_out;

    char* w = (char*)d_ws;
    size_t off = 0;
    auto alloc = [&](size_t bytes) -> void* {
        void* p = w + off;
        off += (bytes + 255) & ~(size_t)255;
        return p;
    };
    f16*   embT  = (f16*)alloc((size_t)VOCAB * KP * sizeof(f16));      // 6.4 MB
    f16*   Wpk   = (f16*)alloc((size_t)1520 * 64 * 8 * sizeof(f16));   // 1.56 MB
    float* biasp = (float*)alloc((size_t)G4 * sizeof(float));
    float* Wc    = (float*)alloc((size_t)2 * GP * sizeof(float));
    float* hlast = (float*)alloc((size_t)B_SZ * GP * sizeof(float));   // 5.0 MB
    float* embG  = (float*)(w + off);                                  // 48.6 MB (f32 [V][1216])
    size_t need_split = off + ((size_t)VOCAB * G4 * sizeof(float) + 255);
    bool split = (ws_size >= need_split);          // deterministic per run

    kP0<<<VOCAB, KP, 0, stream>>>(embed_w, embT);
    kPW2<<<1520, 64, 0, stream>>>(W_ih, W_hh, b_ih, b_hh, Wpk, biasp);
    kP2<<<1, 64, 0, stream>>>(cls_v, cls_g, Wc);
    if (split) {
        kX<<<VOCAB / 16, 512, 0, stream>>>(embT, Wpk, biasp, embG);
        kR9<<<NBLK, 512, 0, stream>>>(cap, cap_len, embG, Wpk, hlast);
    } else {
        static const int smem_bytes = 67072 + 64;
        (void)hipFuncSetAttribute((const void*)kR8,
                                  hipFuncAttributeMaxDynamicSharedMemorySize, smem_bytes);
        kR8<<<NBLK, 512, smem_bytes, stream>>>(cap, cap_len, embT, Wpk, biasp, hlast);
    }
    kC<<<B_SZ, 64, 0, stream>>>(hlast, Wc, cls_b, out);
}

// Round 11
// 487.627 us; speedup vs baseline: 2.0819x; 1.0049x over previous
//
#include <hip/hip_runtime.h>
#include <hip/hip_fp16.h>

typedef _Float16 f16;
typedef _Float16 f16x4 __attribute__((ext_vector_type(4)));
typedef _Float16 f16x8 __attribute__((ext_vector_type(8)));
typedef float f32x4 __attribute__((ext_vector_type(4)));

#define B_SZ   4096
#define T_SZ   32
#define VOCAB  10000
#define E_SZ   300
#define H_SZ   300
#define KP     320          // embT row width (10x32)
#define GP     304          // per-gate padded N (19x16)
#define G4     1216         // 4*GP
#define LDA    328          // hbuf row stride f16 (16B-aligned rows)
#define LDG    1224         // kR8 gates row stride f16
#define LDG2   1224         // kR10 interleaved gates row stride f16 ([j][4] cols + pad)
#define ROWS   16           // batch rows per block
#define NBLK   (B_SZ/ROWS)  // 256 blocks -> 1 per CU

__device__ __forceinline__ float sigmoid_f(float x) {
    return 1.f / (1.f + __expf(-x));
}
__device__ __forceinline__ float tanh_f(float x) {
    x = fminf(fmaxf(x, -15.f), 15.f);
    float e = __expf(2.f * x);
    return (e - 1.f) / (e + 1.f);
}

// P0: embed_w f32 [V][300] -> embT f16 [V][320] zero-padded
__global__ void kP0(const float* __restrict__ ew, f16* __restrict__ embT) {
    int v = blockIdx.x, k = threadIdx.x;           // 320 threads
    embT[(size_t)v * KP + k] = (k < E_SZ) ? (f16)ew[(size_t)v * E_SZ + k] : (f16)0.f;
}

// kPW2: pack weights into MFMA-B-fragment order, coalesced.
__global__ void kPW2(const float* __restrict__ wih, const float* __restrict__ whh,
                     const float* __restrict__ bih, const float* __restrict__ bhh,
                     f16* __restrict__ Wpk, float* __restrict__ biasp) {
    int bid = blockIdx.x;                          // 0..1519 = (gate*19+nt)*20+k
    int lane = threadIdx.x;                        // 64
    int k = bid % 20, ntg = bid / 20;
    int nt = ntg % 19, gate = ntg / 19;
    int c = lane & 15, q = lane >> 4;
    int j = nt * 16 + c;                           // 0..303
    int src = gate * H_SZ + j;
    f16 vals[8];
#pragma unroll
    for (int jj = 0; jj < 8; ++jj) {
        int kk = k * 32 + q * 8 + jj;
        float v = 0.f;
        if (j < H_SZ) {
            if (kk < KP) { if (kk < H_SZ) v = whh[(size_t)src * H_SZ + kk]; }
            else { int kx = kk - KP; if (kx < E_SZ) v = wih[(size_t)src * E_SZ + kx]; }
        }
        vals[jj] = (f16)v;
    }
    *(f16x8*)(Wpk + ((size_t)bid * 64 + lane) * 8) = *(const f16x8*)vals;
    if (k == 0 && q == 0)
        biasp[gate * GP + j] = (j < H_SZ) ? (bih[src] + bhh[src]) : 0.f;
}

// P2: weight-normed classifier W = g * v / ||v||  -> Wc f32 [2][GP]
__global__ void kP2(const float* __restrict__ cls_v, const float* __restrict__ cls_g,
                    float* __restrict__ Wc) {
    int lane = threadIdx.x;                        // 64
    for (int cl = 0; cl < 2; ++cl) {
        float s = 0.f;
        for (int j = lane; j < H_SZ; j += 64) { float v = cls_v[cl * H_SZ + j]; s += v * v; }
        for (int off = 32; off; off >>= 1) s += __shfl_down(s, off);
        float nrm = sqrtf(__shfl(s, 0));
        float scale = cls_g[cl] / nrm;
        for (int j = lane; j < H_SZ; j += 64) Wc[cl * GP + j] = cls_v[cl * H_SZ + j] * scale;
    }
}

// kX2: per-vocab x-gate preacts, gate-interleaved f16:
// embX[v][j][gate] = (W_ih . emb[v] + b_ih + b_hh)[gate*300+j]
__global__ __launch_bounds__(512, 2)
void kX2(const f16* __restrict__ embT, const f16* __restrict__ Wpk,
         const float* __restrict__ biasp, f16* __restrict__ embX) {
    int tid = threadIdx.x;
    int v0 = blockIdx.x * 16;
    int wave = tid >> 6, lane = tid & 63;
    int c = lane & 15, q = lane >> 4;
    int gate = wave >> 1, half = wave & 1;
    int nt0 = half * 10, ntiles = half ? 9 : 10;   // 19 = 10 + 9
    const f16* wp0 = Wpk + (((size_t)(gate * 19 + nt0) * 20 + 10) * 64 + lane) * 8;
    f16x8 afr[10];
    const f16* arow = embT + (size_t)(v0 + c) * KP + q * 8;
#pragma unroll
    for (int k = 0; k < 10; ++k)
        afr[k] = *(const f16x8*)(arow + k * 32);
    f16x8 buf[10];
#pragma unroll
    for (int s = 0; s < 10; ++s)
        buf[s] = *(const f16x8*)(wp0 + (size_t)s * 512);
#pragma unroll 1
    for (int nt = 0; nt < ntiles - 1; ++nt) {
        int jcol = (nt0 + nt) * 16 + c;
        float bia = biasp[gate * GP + jcol];
        f32x4 acc = {bia, bia, bia, bia};
#pragma unroll
        for (int k = 0; k < 10; ++k) {
            acc = __builtin_amdgcn_mfma_f32_16x16x32_f16(afr[k], buf[k], acc, 0, 0, 0);
            buf[k] = *(const f16x8*)(wp0 + (size_t)(nt * 20 + k + 20) * 512);
        }
#pragma unroll
        for (int r = 0; r < 4; ++r)
            embX[((size_t)(v0 + q * 4 + r) * GP + jcol) * 4 + gate] = (f16)acc[r];
    }
    {
        int nt = ntiles - 1;
        int jcol = (nt0 + nt) * 16 + c;
        float bia = biasp[gate * GP + jcol];
        f32x4 acc = {bia, bia, bia, bia};
#pragma unroll
        for (int k = 0; k < 10; ++k)
            acc = __builtin_amdgcn_mfma_f32_16x16x32_f16(afr[k], buf[k], acc, 0, 0, 0);
#pragma unroll
        for (int r = 0; r < 4; ++r)
            embX[((size_t)(v0 + q * 4 + r) * GP + jcol) * 4 + gate] = (f16)acc[r];
    }
}

// kR10: W_hh-only recurrence. 256 blocks x 512 thr (8 waves), 16 rows/block.
// Phase 1 as kR9 (10-slot pipelined weight stream) but gates stored
// gate-interleaved [m][j][4]; phase 2 does ONE ds_read_b64 + ONE 8B global
// (embX f16x4) per element.
__global__ __launch_bounds__(512, 2)
void kR10(const int* __restrict__ cap,
          const int* __restrict__ cap_len,
          const f16* __restrict__ embX,
          const f16* __restrict__ Wpk,
          float* __restrict__ hlast) {
    __shared__ __align__(16) f16 hbuf[ROWS * LDA];      // 10496 B
    __shared__ __align__(16) f16 gatesI[ROWS * LDG2];   // 39168 B, [m][j][4]+pad
    __shared__ int capv[ROWS * T_SZ];                   // 2048 B
    __shared__ int lens[ROWS];                          // 64 B
    int tid = threadIdx.x;
    int b0 = blockIdx.x * ROWS;
    if (tid < ROWS) lens[tid] = cap_len[b0 + tid];
    for (int i = tid; i < ROWS * T_SZ; i += 512) capv[i] = cap[(size_t)b0 * T_SZ + i];
    for (int i = tid; i < ROWS * LDA; i += 512) hbuf[i] = (f16)0.f;  // pads stay 0
    __syncthreads();
    int wave = tid >> 6, lane = tid & 63;
    int c = lane & 15, q = lane >> 4;
    int gate = wave >> 1, half = wave & 1;
    int nt0 = half * 10, ntiles = half ? 9 : 10;   // 19 = 10 + 9
    const f16* wp0 = Wpk + ((size_t)((gate * 19 + nt0) * 20) * 64 + lane) * 8;  // W_hh blocks
    const f16* hrow = hbuf + c * LDA + q * 8;
    float creg[10];                                 // per-thread c-state, idx map fixed over t
#pragma unroll
    for (int i = 0; i < 10; ++i) creg[i] = 0.f;

    for (int t = 0; t < T_SZ; ++t) {
        // --- phase 1: h-preacts = h @ W_hh^T ---
        f16x8 afr[10];
#pragma unroll
        for (int k = 0; k < 10; ++k)
            afr[k] = *(const f16x8*)(hrow + k * 32);
        f16x8 buf[10];
#pragma unroll
        for (int s = 0; s < 10; ++s)
            buf[s] = *(const f16x8*)(wp0 + (size_t)s * 512);
#pragma unroll 1
        for (int nt = 0; nt < ntiles - 1; ++nt) {
            int jcol = (nt0 + nt) * 16 + c;
            f32x4 acc = {0.f, 0.f, 0.f, 0.f};
#pragma unroll
            for (int k = 0; k < 10; ++k) {
                acc = __builtin_amdgcn_mfma_f32_16x16x32_f16(afr[k], buf[k], acc, 0, 0, 0);
                buf[k] = *(const f16x8*)(wp0 + (size_t)(nt * 20 + k + 20) * 512);
            }
#pragma unroll
            for (int r = 0; r < 4; ++r)
                gatesI[(q * 4 + r) * LDG2 + jcol * 4 + gate] = (f16)acc[r];
        }
        {
            int nt = ntiles - 1;
            int jcol = (nt0 + nt) * 16 + c;
            f32x4 acc = {0.f, 0.f, 0.f, 0.f};
#pragma unroll
            for (int k = 0; k < 10; ++k)
                acc = __builtin_amdgcn_mfma_f32_16x16x32_f16(afr[k], buf[k], acc, 0, 0, 0);
#pragma unroll
            for (int r = 0; r < 4; ++r)
                gatesI[(q * 4 + r) * LDG2 + jcol * 4 + gate] = (f16)acc[r];
        }
        __syncthreads();
        // --- phase 2: cell update; x-preacts = one f16x4 per element ---
#pragma unroll
        for (int it = 0; it < 10; ++it) {
            int idx = tid + it * 512;              // 0..5119 = 16*320
            int m = idx / 320, j = idx - m * 320;
            if (j < H_SZ) {
                int v = capv[m * T_SZ + t];
                f16x4 xi = *(const f16x4*)(embX + ((size_t)v * GP + j) * 4);
                f16x4 hi = *(const f16x4*)(&gatesI[m * LDG2 + j * 4]);
                float gi = (float)hi[0] + (float)xi[0];
                float gf = (float)hi[1] + (float)xi[1];
                float gg = (float)hi[2] + (float)xi[2];
                float go = (float)hi[3] + (float)xi[3];
                float ii = sigmoid_f(gi);
                float ff = sigmoid_f(gf);
                float gt = tanh_f(gg);
                float oo = sigmoid_f(go);
                float cn = ff * creg[it] + ii * gt;
                creg[it] = cn;
                float hh = oo * tanh_f(cn);
                hbuf[m * LDA + j] = (f16)hh;
                if (t == lens[m] - 1) hlast[(size_t)(b0 + m) * GP + j] = hh;
            }
        }
        __syncthreads();
    }
}

// kR8 (fallback, proven 584 us): fused [h|x] recurrence, used when ws too small for embX.
__global__ __launch_bounds__(512, 2)
void kR8(const int* __restrict__ cap,
         const int* __restrict__ cap_len,
         const f16* __restrict__ embT,
         const f16* __restrict__ Wpk,
         const float* __restrict__ biasp,
         float* __restrict__ hlast) {
    extern __shared__ __align__(16) char smem[];
    f16*   hbuf  = (f16*)smem;                          // 10496
    f16*   xbuf  = (f16*)(smem + 10496);                // 10496
    f16*   gates = (f16*)(smem + 20992);                // 39168
    float* biasL = (float*)(smem + 60160);              // 4864
    int*   capv  = (int*)(smem + 65024);                // 2048
    int*   lens  = (int*)(smem + 67072);                // 64
    int tid = threadIdx.x;
    int b0 = blockIdx.x * ROWS;
    if (tid < ROWS) lens[tid] = cap_len[b0 + tid];
    for (int i = tid; i < ROWS * T_SZ; i += 512) capv[i] = cap[(size_t)b0 * T_SZ + i];
    for (int i = tid; i < ROWS * LDA; i += 512) hbuf[i] = (f16)0.f;
    for (int i = tid; i < G4; i += 512) biasL[i] = biasp[i];
    __syncthreads();
    for (int i = tid; i < ROWS * 40; i += 512) {
        int m = i / 40, c8 = i - m * 40;
        int v = capv[m * T_SZ + 0];
        *(f16x8*)(xbuf + m * LDA + c8 * 8) = *(const f16x8*)(embT + (size_t)v * KP + c8 * 8);
    }
    __syncthreads();
    int wave = tid >> 6, lane = tid & 63;
    int c = lane & 15, q = lane >> 4;
    int gate = wave >> 1, half = wave & 1;
    int nt0 = half * 10, ntiles = half ? 9 : 10;
    const f16* wp0 = Wpk + ((size_t)((gate * 19 + nt0) * 20) * 64 + lane) * 8;
    const f16* hrow = hbuf + c * LDA + q * 8;
    const f16* xrow = xbuf + c * LDA + q * 8;
    float creg[10];
#pragma unroll
    for (int i = 0; i < 10; ++i) creg[i] = 0.f;

    for (int t = 0; t < T_SZ; ++t) {
        f16x8 afr[10];
#pragma unroll
        for (int k = 0; k < 10; ++k)
            afr[k] = *(const f16x8*)(hrow + k * 32);
        f16x8 buf[10];
#pragma unroll
        for (int s = 0; s < 10; ++s)
            buf[s] = *(const f16x8*)(wp0 + (size_t)s * 512);
#pragma unroll 1
        for (int nt = 0; nt < ntiles - 1; ++nt) {
            int base = nt * 20;
            int ncol = gate * GP + (nt0 + nt) * 16 + c;
            float bia = biasL[ncol];
            f32x4 acch = {bia, bia, bia, bia};
            f32x4 accx = {0.f, 0.f, 0.f, 0.f};
#pragma unroll
            for (int k = 0; k < 20; ++k) {
                if (k < 10) {
                    acch = __builtin_amdgcn_mfma_f32_16x16x32_f16(afr[k], buf[k % 10], acch, 0, 0, 0);
                } else {
                    f16x8 a = *(const f16x8*)(xrow + (k - 10) * 32);
                    accx = __builtin_amdgcn_mfma_f32_16x16x32_f16(a, buf[k % 10], accx, 0, 0, 0);
                }
                buf[k % 10] = *(const f16x8*)(wp0 + (size_t)(base + k + 10) * 512);
            }
#pragma unroll
            for (int r = 0; r < 4; ++r)
                gates[(q * 4 + r) * LDG + ncol] = (f16)(acch[r] + accx[r]);
        }
        {
            int nt = ntiles - 1;
            int base = nt * 20;
            int ncol = gate * GP + (nt0 + nt) * 16 + c;
            float bia = biasL[ncol];
            f32x4 acch = {bia, bia, bia, bia};
            f32x4 accx = {0.f, 0.f, 0.f, 0.f};
#pragma unroll
            for (int k = 0; k < 20; ++k) {
                if (k < 10) {
                    acch = __builtin_amdgcn_mfma_f32_16x16x32_f16(afr[k], buf[k % 10], acch, 0, 0, 0);
                    buf[k % 10] = *(const f16x8*)(wp0 + (size_t)(base + k + 10) * 512);
                } else {
                    f16x8 a = *(const f16x8*)(xrow + (k - 10) * 32);
                    accx = __builtin_amdgcn_mfma_f32_16x16x32_f16(a, buf[k % 10], accx, 0, 0, 0);
                }
            }
#pragma unroll
            for (int r = 0; r < 4; ++r)
                gates[(q * 4 + r) * LDG + ncol] = (f16)(acch[r] + accx[r]);
        }
        __syncthreads();
        int tp1 = t + 1;
        if (tp1 < T_SZ) {
            for (int i = tid; i < ROWS * 40; i += 512) {
                int m = i / 40, c8 = i - m * 40;
                int v = capv[m * T_SZ + tp1];
                *(f16x8*)(xbuf + m * LDA + c8 * 8) =
                    *(const f16x8*)(embT + (size_t)v * KP + c8 * 8);
            }
        }
#pragma unroll
        for (int it = 0; it < 10; ++it) {
            int idx = tid + it * 512;
            int m = idx / 320, j = idx - m * 320;
            if (j < H_SZ) {
                const f16* gr = gates + m * LDG;
                float gi = (float)gr[j];
                float gf = (float)gr[GP + j];
                float gg = (float)gr[2 * GP + j];
                float go = (float)gr[3 * GP + j];
                float ii = sigmoid_f(gi);
                float ff = sigmoid_f(gf);
                float gt = tanh_f(gg);
                float oo = sigmoid_f(go);
                float cn = ff * creg[it] + ii * gt;
                creg[it] = cn;
                float hh = oo * tanh_f(cn);
                hbuf[m * LDA + j] = (f16)hh;
                if (t == lens[m] - 1) hlast[(size_t)(b0 + m) * GP + j] = hh;
            }
        }
        __syncthreads();
    }
}

// kC: out[row][cl] = hlast[row] . Wc[cl] + cls_b[cl]
__global__ void kC(const float* __restrict__ hlast, const float* __restrict__ Wc,
                   const float* __restrict__ cls_b, float* __restrict__ out) {
    int row = blockIdx.x, lane = threadIdx.x;      // 64 threads
    const float* h = hlast + (size_t)row * GP;
    float s0 = 0.f, s1 = 0.f;
    for (int j = lane; j < H_SZ; j += 64) {
        float hv = h[j];
        s0 += hv * Wc[j];
        s1 += hv * Wc[GP + j];
    }
    for (int off = 32; off; off >>= 1) {
        s0 += __shfl_down(s0, off);
        s1 += __shfl_down(s1, off);
    }
    if (lane == 0) {
        out[row * 2 + 0] = s0 + cls_b[0];
        out[row * 2 + 1] = s1 + cls_b[1];
    }
}

extern "C" void kernel_launch(void* const* d_in, const int* in_sizes, int n_in,
                              void* d_out, int out_size, void* d_ws, size_t ws_size,
                              hipStream_t stream) {
    const int*   cap     = (const int*)d_in[0];
    const int*   cap_len = (const int*)d_in[1];
    const float* embed_w = (const float*)d_in[2];
    const float* W_ih    = (const float*)d_in[3];
    const float* W_hh    = (const float*)d_in[4];
    const float* b_ih    = (const float*)d_in[5];
    const float* b_hh    = (const float*)d_in[6];
    const float* cls_v   = (const float*)d_in[7];
    const float* cls_g   = (const float*)d_in[8];
    const float* cls_b   = (const float*)d_in[9];
    float* out = (float*)d_out;

    char* w = (char*)d_ws;
    size_t off = 0;
    auto alloc = [&](size_t bytes) -> void* {
        void* p = w + off;
        off += (bytes + 255) & ~(size_t)255;
        return p;
    };
    f16*   embT  = (f16*)alloc((size_t)VOCAB * KP * sizeof(f16));      // 6.4 MB
    f16*   Wpk   = (f16*)alloc((size_t)1520 * 64 * 8 * sizeof(f16));   // 1.56 MB
    float* biasp = (float*)alloc((size_t)G4 * sizeof(float));
    float* Wc    = (float*)alloc((size_t)2 * GP * sizeof(float));
    float* hlast = (float*)alloc((size_t)B_SZ * GP * sizeof(float));   // 5.0 MB
    f16*   embX  = (f16*)(w + off);                                    // 24.3 MB f16 [V][GP][4]
    size_t need_split = off + ((size_t)VOCAB * GP * 4 * sizeof(f16) + 255);
    bool split = (ws_size >= need_split);          // deterministic per run

    kP0<<<VOCAB, KP, 0, stream>>>(embed_w, embT);
    kPW2<<<1520, 64, 0, stream>>>(W_ih, W_hh, b_ih, b_hh, Wpk, biasp);
    kP2<<<1, 64, 0, stream>>>(cls_v, cls_g, Wc);
    if (split) {
        kX2<<<VOCAB / 16, 512, 0, stream>>>(embT, Wpk, biasp, embX);
        kR10<<<NBLK, 512, 0, stream>>>(cap, cap_len, embX, Wpk, hlast);
    } else {
        static const int smem_bytes = 67072 + 64;
        (void)hipFuncSetAttribute((const void*)kR8,
                                  hipFuncAttributeMaxDynamicSharedMemorySize, smem_bytes);
        kR8<<<NBLK, 512, smem_bytes, stream>>>(cap, cap_len, embT, Wpk, biasp, hlast);
    }
    kC<<<B_SZ, 64, 0, stream>>>(hlast, Wc, cls_b, out);
}